// Round 1
// baseline (221.081 us; speedup 1.0000x reference)
//
#include <hip/hip_runtime.h>

typedef __attribute__((ext_vector_type(8))) short short8;
typedef __attribute__((ext_vector_type(4))) float f32x4;

#define B_ 4
#define N_ 4096
#define E_ 256
#define D_ 64
#define SCALE 0.125f          // 1/sqrt(D)
#define MASKVAL (-1e30f)      // exact-equality mask value (see theory)

static __device__ __forceinline__ unsigned short f2bf(float f) {
  union { float f; unsigned int u; } v; v.f = f;
  return (unsigned short)((v.u + 0x7fffu + ((v.u >> 16) & 1u)) >> 16);  // RNE
}

// ---------------------------------------------------------------------------
// Projection: out = X @ W^T  (X:[B*N,256] f32, W:[64,256] f32) -> bf16
// p=0: q [B*N][64] row-major; p=1: k [B*N][64] row-major; p=2: vT [B][64][N]
// Block: 256 threads, 64 rows of X. LDS tiles padded to 264 ushort/row
// (row stride 528B = 33*16B -> A/B-frag ds_read_b128 lands 2-way, free).
// ---------------------------------------------------------------------------
__global__ __launch_bounds__(256) void proj_kernel(
    const float* __restrict__ Qv, const float* __restrict__ Kv,
    const float* __restrict__ Vv, const float* __restrict__ Wq,
    const float* __restrict__ Wk, const float* __restrict__ Wv,
    unsigned short* __restrict__ qo, unsigned short* __restrict__ ko,
    unsigned short* __restrict__ vto)
{
  const int p  = blockIdx.y;
  const int rb = blockIdx.x;            // 64-row block over B*N (4096%64==0)
  const int t  = threadIdx.x;

  __align__(16) __shared__ unsigned short Xl[64 * 264];
  __align__(16) __shared__ unsigned short Wl[64 * 264];

  const float* xsrc = (p == 0 ? Qv : (p == 1 ? Kv : Vv)) + (size_t)rb * 64 * E_;
  const float* wsrc = (p == 0 ? Wq : (p == 1 ? Wk : Wv));

  // Stage X tile and W (both 64x256 f32 -> bf16), coalesced flat loads.
  #pragma unroll
  for (int it = 0; it < 8; ++it) {
    int idx = it * 2048 + t * 8;
    int row = idx >> 8, col = idx & 255;
    float4 a0 = *(const float4*)(xsrc + idx);
    float4 a1 = *(const float4*)(xsrc + idx + 4);
    uint4 wx;
    wx.x = (unsigned)f2bf(a0.x) | ((unsigned)f2bf(a0.y) << 16);
    wx.y = (unsigned)f2bf(a0.z) | ((unsigned)f2bf(a0.w) << 16);
    wx.z = (unsigned)f2bf(a1.x) | ((unsigned)f2bf(a1.y) << 16);
    wx.w = (unsigned)f2bf(a1.z) | ((unsigned)f2bf(a1.w) << 16);
    *(uint4*)&Xl[row * 264 + col] = wx;
    float4 b0 = *(const float4*)(wsrc + idx);
    float4 b1 = *(const float4*)(wsrc + idx + 4);
    uint4 ww;
    ww.x = (unsigned)f2bf(b0.x) | ((unsigned)f2bf(b0.y) << 16);
    ww.y = (unsigned)f2bf(b0.z) | ((unsigned)f2bf(b0.w) << 16);
    ww.z = (unsigned)f2bf(b1.x) | ((unsigned)f2bf(b1.y) << 16);
    ww.w = (unsigned)f2bf(b1.z) | ((unsigned)f2bf(b1.w) << 16);
    *(uint4*)&Wl[row * 264 + col] = ww;
  }
  __syncthreads();

  const int wave = t >> 6, lane = t & 63, g = lane >> 4, lq = lane & 15;
  // p<2: C[n][d] = X*W^T  (A=X rows, B cols=d from W rows)
  // p==2: C[d][n] = W*X^T (A=W rows, B cols=n from X rows)  -> writes vT directly
  const unsigned short* TA = (p == 2) ? Wl : Xl;
  const unsigned short* TB = (p == 2) ? Xl : Wl;

  f32x4 acc0 = {0.f,0.f,0.f,0.f}, acc1 = acc0, acc2 = acc0, acc3 = acc0;
  #pragma unroll
  for (int kc = 0; kc < 8; ++kc) {
    short8 af = *(const short8*)&TA[(wave * 16 + lq) * 264 + kc * 32 + g * 8];
    short8 b0 = *(const short8*)&TB[(0 * 16 + lq) * 264 + kc * 32 + g * 8];
    acc0 = __builtin_amdgcn_mfma_f32_16x16x32_bf16(af, b0, acc0, 0, 0, 0);
    short8 b1 = *(const short8*)&TB[(1 * 16 + lq) * 264 + kc * 32 + g * 8];
    acc1 = __builtin_amdgcn_mfma_f32_16x16x32_bf16(af, b1, acc1, 0, 0, 0);
    short8 b2 = *(const short8*)&TB[(2 * 16 + lq) * 264 + kc * 32 + g * 8];
    acc2 = __builtin_amdgcn_mfma_f32_16x16x32_bf16(af, b2, acc2, 0, 0, 0);
    short8 b3 = *(const short8*)&TB[(3 * 16 + lq) * 264 + kc * 32 + g * 8];
    acc3 = __builtin_amdgcn_mfma_f32_16x16x32_bf16(af, b3, acc3, 0, 0, 0);
  }

  // C/D layout (HW-verified): col = lane&15, row = (lane>>4)*4 + reg
  if (p < 2) {
    unsigned short* dst = (p == 0 ? qo : ko);
    #pragma unroll
    for (int c = 0; c < 4; ++c) {
      const f32x4 ac = (c == 0 ? acc0 : c == 1 ? acc1 : c == 2 ? acc2 : acc3);
      #pragma unroll
      for (int r = 0; r < 4; ++r) {
        int n = rb * 64 + wave * 16 + g * 4 + r;
        dst[(size_t)n * D_ + c * 16 + lq] = f2bf(ac[r]);
      }
    }
  } else {
    int bb = (rb * 64) >> 12;           // batch (blocks never straddle batches)
    #pragma unroll
    for (int c = 0; c < 4; ++c) {
      const f32x4 ac = (c == 0 ? acc0 : c == 1 ? acc1 : c == 2 ? acc2 : acc3);
      #pragma unroll
      for (int r = 0; r < 4; ++r) {
        int d = wave * 16 + g * 4 + r;
        int n = (rb * 64 + c * 16 + lq) & (N_ - 1);
        vto[((size_t)bb * D_ + d) * N_ + n] = f2bf(ac[r]);
      }
    }
  }
}

// ---------------------------------------------------------------------------
// Flash attention. Block = 4 waves x 16 q-rows (64 q/block). KV tile = 32.
// Swapped QK^T: S^T = mfma(K_frag, Q_frag) -> lane&15 = q-row, softmax is
// 8 local values + shfl_xor(16,32). LDS rows padded (K:144B, VT:80B, P:80B)
// to keep ds_read_b128 at <=2-way bank aliasing (free per m136).
// ---------------------------------------------------------------------------
__global__ __launch_bounds__(256) void attn_kernel(
    const unsigned short* __restrict__ q, const unsigned short* __restrict__ kk,
    const unsigned short* __restrict__ vt, const int* __restrict__ mask,
    float* __restrict__ out)
{
  const int b = blockIdx.y;
  const int t = threadIdx.x;
  const int wave = t >> 6, lane = t & 63, g = lane >> 4, lq = lane & 15;
  const int qbase = blockIdx.x * 64 + wave * 16;

  __align__(16) __shared__ unsigned short KtL[32 * 72];   // [key][72] (144B rows)
  __align__(16) __shared__ unsigned short VtL[64 * 40];   // [d][40]   (80B rows)
  __align__(16) __shared__ unsigned short Pl[4][16 * 40]; // per-wave P [q][40]
  __shared__ float keepf[32];

  // Q fragments (row = lq, k-dim = d), held for the whole kernel
  const size_t qrow = (size_t)(b * N_ + qbase + lq) * D_;
  short8 qf0 = *(const short8*)&q[qrow + g * 8];
  short8 qf1 = *(const short8*)&q[qrow + 32 + g * 8];
  const int mq = mask[b * N_ + qbase + lq];
  const int qg = qbase + lq;

  float m = -INFINITY, lsum = 0.f;
  f32x4 o0 = {0.f,0.f,0.f,0.f}, o1 = o0, o2 = o0, o3 = o0;

  const int srow = t >> 3, sblk = t & 7;   // K staging: 32 rows x 8 blocks
  const int vrow = t >> 2, vblk = t & 3;   // VT staging: 64 rows x 4 blocks

  for (int jt = 0; jt < N_ / 32; ++jt) {
    const int jbase = jt * 32;
    __syncthreads();
    *(uint4*)&KtL[srow * 72 + sblk * 8] =
        *(const uint4*)&kk[(size_t)(b * N_ + jbase + srow) * D_ + sblk * 8];
    *(uint4*)&VtL[vrow * 40 + vblk * 8] =
        *(const uint4*)&vt[((size_t)b * D_ + vrow) * N_ + jbase + vblk * 8];
    if (t < 32) keepf[t] = mask[b * N_ + jbase + t] ? 1.f : 0.f;
    __syncthreads();

    // S^T: rows = keys, cols = q. A = K rows, B = Q^T.
    f32x4 st0 = {0.f,0.f,0.f,0.f}, st1 = st0;
    {
      short8 ka = *(const short8*)&KtL[lq * 72 + g * 8];
      short8 kb = *(const short8*)&KtL[lq * 72 + 32 + g * 8];
      st0 = __builtin_amdgcn_mfma_f32_16x16x32_bf16(ka, qf0, st0, 0, 0, 0);
      st0 = __builtin_amdgcn_mfma_f32_16x16x32_bf16(kb, qf1, st0, 0, 0, 0);
      short8 kc = *(const short8*)&KtL[(16 + lq) * 72 + g * 8];
      short8 kd = *(const short8*)&KtL[(16 + lq) * 72 + 32 + g * 8];
      st1 = __builtin_amdgcn_mfma_f32_16x16x32_bf16(kc, qf0, st1, 0, 0, 0);
      st1 = __builtin_amdgcn_mfma_f32_16x16x32_bf16(kd, qf1, st1, 0, 0, 0);
    }

    // mask + scale; lane holds keys {16c + 4g + r}
    float sv[8];
    float tm = -INFINITY;
    #pragma unroll
    for (int c = 0; c < 2; ++c) {
      #pragma unroll
      for (int r = 0; r < 4; ++r) {
        int kl = c * 16 + g * 4 + r;
        float s = (c ? st1[r] : st0[r]) * SCALE;
        bool valid = (mq != 0) && (keepf[kl] != 0.f) && ((jbase + kl) != qg);
        s = valid ? s : MASKVAL;
        sv[c * 4 + r] = s;
        tm = fmaxf(tm, s);
      }
    }
    tm = fmaxf(tm, __shfl_xor(tm, 16, 64));
    tm = fmaxf(tm, __shfl_xor(tm, 32, 64));
    float mnew = fmaxf(m, tm);
    float corr = __expf(m - mnew);

    float ps = 0.f;
    unsigned int pw[4];
    #pragma unroll
    for (int c = 0; c < 2; ++c) {
      #pragma unroll
      for (int h = 0; h < 2; ++h) {
        float pa = __expf(sv[c * 4 + h * 2 + 0] - mnew);
        float pb = __expf(sv[c * 4 + h * 2 + 1] - mnew);
        ps += pa + pb;
        pw[c * 2 + h] = (unsigned)f2bf(pa) | ((unsigned)f2bf(pb) << 16);
      }
    }
    ps += __shfl_xor(ps, 16, 64);
    ps += __shfl_xor(ps, 32, 64);
    lsum = lsum * corr + ps;
    m = mnew;

    // P to per-wave LDS: [q = lq][key col = 16c + 4g + r], then read A-frag.
    uint2 w0; w0.x = pw[0]; w0.y = pw[1];
    uint2 w1; w1.x = pw[2]; w1.y = pw[3];
    *(uint2*)&Pl[wave][lq * 40 + g * 4]      = w0;
    *(uint2*)&Pl[wave][lq * 40 + 16 + g * 4] = w1;
    asm volatile("s_waitcnt lgkmcnt(0)" ::: "memory");
    __builtin_amdgcn_sched_barrier(0);

    // rescale O (O rows q = 4g + r, so broadcast corr via shfl)
    float c0 = __shfl(corr, g * 4 + 0, 64);
    float c1 = __shfl(corr, g * 4 + 1, 64);
    float c2 = __shfl(corr, g * 4 + 2, 64);
    float c3 = __shfl(corr, g * 4 + 3, 64);
    o0[0] *= c0; o0[1] *= c1; o0[2] *= c2; o0[3] *= c3;
    o1[0] *= c0; o1[1] *= c1; o1[2] *= c2; o1[3] *= c3;
    o2[0] *= c0; o2[1] *= c1; o2[2] *= c2; o2[3] *= c3;
    o3[0] *= c0; o3[1] *= c1; o3[2] *= c2; o3[3] *= c3;

    short8 pf = *(const short8*)&Pl[wave][lq * 40 + g * 8];
    short8 v0 = *(const short8*)&VtL[(0 * 16 + lq) * 40 + g * 8];
    o0 = __builtin_amdgcn_mfma_f32_16x16x32_bf16(pf, v0, o0, 0, 0, 0);
    short8 v1 = *(const short8*)&VtL[(1 * 16 + lq) * 40 + g * 8];
    o1 = __builtin_amdgcn_mfma_f32_16x16x32_bf16(pf, v1, o1, 0, 0, 0);
    short8 v2 = *(const short8*)&VtL[(2 * 16 + lq) * 40 + g * 8];
    o2 = __builtin_amdgcn_mfma_f32_16x16x32_bf16(pf, v2, o2, 0, 0, 0);
    short8 v3 = *(const short8*)&VtL[(3 * 16 + lq) * 40 + g * 8];
    o3 = __builtin_amdgcn_mfma_f32_16x16x32_bf16(pf, v3, o3, 0, 0, 0);
  }

  // epilogue: divide by l per q-row, write f32 out [b][n][d]
  float i0 = 1.f / __shfl(lsum, g * 4 + 0, 64);
  float i1 = 1.f / __shfl(lsum, g * 4 + 1, 64);
  float i2 = 1.f / __shfl(lsum, g * 4 + 2, 64);
  float i3 = 1.f / __shfl(lsum, g * 4 + 3, 64);
  #pragma unroll
  for (int c = 0; c < 4; ++c) {
    const f32x4 oc = (c == 0 ? o0 : c == 1 ? o1 : c == 2 ? o2 : o3);
    size_t base = (size_t)(b * N_ + qbase + g * 4) * D_ + c * 16 + lq;
    out[base + 0 * D_] = oc[0] * i0;
    out[base + 1 * D_] = oc[1] * i1;
    out[base + 2 * D_] = oc[2] * i2;
    out[base + 3 * D_] = oc[3] * i3;
  }
}

// ---------------------------------------------------------------------------
extern "C" void kernel_launch(void* const* d_in, const int* in_sizes, int n_in,
                              void* d_out, int out_size, void* d_ws, size_t ws_size,
                              hipStream_t stream) {
  (void)in_sizes; (void)n_in; (void)out_size; (void)ws_size;
  const float* Qv = (const float*)d_in[0];
  const float* Kv = (const float*)d_in[1];
  const float* Vv = (const float*)d_in[2];
  const int* mask = (const int*)d_in[3];   // bool -> int32 per harness convention
  const float* Wq = (const float*)d_in[4];
  const float* Wk = (const float*)d_in[5];
  const float* Wv = (const float*)d_in[6];
  float* out = (float*)d_out;

  unsigned short* qb  = (unsigned short*)d_ws;                   // [B*N][64] bf16
  unsigned short* kb  = qb + (size_t)B_ * N_ * D_;               // [B*N][64] bf16
  unsigned short* vtb = kb + (size_t)B_ * N_ * D_;               // [B][64][N] bf16

  proj_kernel<<<dim3(256, 3), dim3(256), 0, stream>>>(Qv, Kv, Vv, Wq, Wk, Wv,
                                                      qb, kb, vtb);
  attn_kernel<<<dim3(N_ / 64, B_), dim3(256), 0, stream>>>(qb, kb, vtb, mask, out);
}

// Round 2
// 69.982 us; speedup vs baseline: 3.1591x; 3.1591x over previous
//
#include <hip/hip_runtime.h>
#include <math.h>

typedef __attribute__((ext_vector_type(8))) short short8;
typedef __attribute__((ext_vector_type(4))) float f32x4;
typedef unsigned short ushort_t;

#define B_ 4
#define N_ 4096
#define E_ 256
#define D_ 64
#define SCALE 0.125f          // 1/sqrt(D)
#define MASKVAL (-1e30f)      // additive mask; f32 absorption makes score-1e30 == -1e30 exactly

static __device__ __forceinline__ unsigned short f2bf(float f) {
  union { float f; unsigned int u; } v; v.f = f;
  return (unsigned short)((v.u + 0x7fffu + ((v.u >> 16) & 1u)) >> 16);  // RNE
}

// ---------------------------------------------------------------------------
// Projection: out = X @ W^T  (X:[B*N,256] f32, W:[64,256] f32) -> bf16
// p=0: q [B*N][64]; p=1: k [B*N][64]; p=2: vT [B][64][N].
// p=0 also folds the mask -> additive-bias f32 array (0 or -1e30).
// ---------------------------------------------------------------------------
__global__ __launch_bounds__(256) void proj_kernel(
    const float* __restrict__ Qv, const float* __restrict__ Kv,
    const float* __restrict__ Vv, const float* __restrict__ Wq,
    const float* __restrict__ Wk, const float* __restrict__ Wv,
    const int* __restrict__ mask,
    unsigned short* __restrict__ qo, unsigned short* __restrict__ ko,
    unsigned short* __restrict__ vto, float* __restrict__ biasf)
{
  const int p  = blockIdx.y;
  const int rb = blockIdx.x;            // 64-row block over B*N
  const int t  = threadIdx.x;

  __align__(16) __shared__ unsigned short Xl[64 * 264];
  __align__(16) __shared__ unsigned short Wl[64 * 264];

  const float* xsrc = (p == 0 ? Qv : (p == 1 ? Kv : Vv)) + (size_t)rb * 64 * E_;
  const float* wsrc = (p == 0 ? Wq : (p == 1 ? Wk : Wv));

  if (p == 0 && t < 64) biasf[rb * 64 + t] = mask[rb * 64 + t] ? 0.f : MASKVAL;

  #pragma unroll
  for (int it = 0; it < 8; ++it) {
    int idx = it * 2048 + t * 8;
    int row = idx >> 8, col = idx & 255;
    float4 a0 = *(const float4*)(xsrc + idx);
    float4 a1 = *(const float4*)(xsrc + idx + 4);
    uint4 wx;
    wx.x = (unsigned)f2bf(a0.x) | ((unsigned)f2bf(a0.y) << 16);
    wx.y = (unsigned)f2bf(a0.z) | ((unsigned)f2bf(a0.w) << 16);
    wx.z = (unsigned)f2bf(a1.x) | ((unsigned)f2bf(a1.y) << 16);
    wx.w = (unsigned)f2bf(a1.z) | ((unsigned)f2bf(a1.w) << 16);
    *(uint4*)&Xl[row * 264 + col] = wx;
    float4 b0 = *(const float4*)(wsrc + idx);
    float4 b1 = *(const float4*)(wsrc + idx + 4);
    uint4 ww;
    ww.x = (unsigned)f2bf(b0.x) | ((unsigned)f2bf(b0.y) << 16);
    ww.y = (unsigned)f2bf(b0.z) | ((unsigned)f2bf(b0.w) << 16);
    ww.z = (unsigned)f2bf(b1.x) | ((unsigned)f2bf(b1.y) << 16);
    ww.w = (unsigned)f2bf(b1.z) | ((unsigned)f2bf(b1.w) << 16);
    *(uint4*)&Wl[row * 264 + col] = ww;
  }
  __syncthreads();

  const int wave = t >> 6, lane = t & 63, g = lane >> 4, lq = lane & 15;
  const unsigned short* TA = (p == 2) ? Wl : Xl;
  const unsigned short* TB = (p == 2) ? Xl : Wl;

  f32x4 acc0 = {0.f,0.f,0.f,0.f}, acc1 = acc0, acc2 = acc0, acc3 = acc0;
  #pragma unroll
  for (int kc = 0; kc < 8; ++kc) {
    short8 af = *(const short8*)&TA[(wave * 16 + lq) * 264 + kc * 32 + g * 8];
    short8 b0 = *(const short8*)&TB[(0 * 16 + lq) * 264 + kc * 32 + g * 8];
    acc0 = __builtin_amdgcn_mfma_f32_16x16x32_bf16(af, b0, acc0, 0, 0, 0);
    short8 b1 = *(const short8*)&TB[(1 * 16 + lq) * 264 + kc * 32 + g * 8];
    acc1 = __builtin_amdgcn_mfma_f32_16x16x32_bf16(af, b1, acc1, 0, 0, 0);
    short8 b2 = *(const short8*)&TB[(2 * 16 + lq) * 264 + kc * 32 + g * 8];
    acc2 = __builtin_amdgcn_mfma_f32_16x16x32_bf16(af, b2, acc2, 0, 0, 0);
    short8 b3 = *(const short8*)&TB[(3 * 16 + lq) * 264 + kc * 32 + g * 8];
    acc3 = __builtin_amdgcn_mfma_f32_16x16x32_bf16(af, b3, acc3, 0, 0, 0);
  }

  if (p < 2) {
    unsigned short* dst = (p == 0 ? qo : ko);
    #pragma unroll
    for (int c = 0; c < 4; ++c) {
      const f32x4 ac = (c == 0 ? acc0 : c == 1 ? acc1 : c == 2 ? acc2 : acc3);
      #pragma unroll
      for (int r = 0; r < 4; ++r) {
        int n = rb * 64 + wave * 16 + g * 4 + r;
        dst[(size_t)n * D_ + c * 16 + lq] = f2bf(ac[r]);
      }
    }
  } else {
    int bb = (rb * 64) >> 12;
    #pragma unroll
    for (int c = 0; c < 4; ++c) {
      const f32x4 ac = (c == 0 ? acc0 : c == 1 ? acc1 : c == 2 ? acc2 : acc3);
      #pragma unroll
      for (int r = 0; r < 4; ++r) {
        int d = wave * 16 + g * 4 + r;
        int n = (rb * 64 + c * 16 + lq) & (N_ - 1);
        vto[((size_t)bb * D_ + d) * N_ + n] = f2bf(ac[r]);
      }
    }
  }
}

// ---------------------------------------------------------------------------
// Flash attention, KV-split. Block = 4 waves x 16 q-rows; key tile = 64;
// double-buffered LDS (T14 async-stage: issue loads early, ds_write late,
// one barrier per tile); T2 XOR-swizzled K/V tiles (16B-chunk ^ row&7).
// Writes unnormalized O' [64q][64d] f32 + (m,l) per q-row; merge normalizes.
// ---------------------------------------------------------------------------
__global__ __launch_bounds__(256, 3) void attn2_kernel(
    const ushort_t* __restrict__ q, const ushort_t* __restrict__ kk,
    const ushort_t* __restrict__ vt, const float* __restrict__ biasf,
    float* __restrict__ op0, float* __restrict__ opws,
    float* __restrict__ mlbuf, int nsplit)
{
  const int b = blockIdx.y, qt = blockIdx.x, sp = blockIdx.z;
  const int t = threadIdx.x;
  const int wave = t >> 6, lane = t & 63, g = lane >> 4, lq = lane & 15;

  const int TT = N_ / 64;                          // key tiles per batch
  const int tile_lo = (sp * TT) / nsplit;
  const int tile_hi = ((sp + 1) * TT) / nsplit;
  const int nit = tile_hi - tile_lo;

  __align__(16) __shared__ ushort_t Kt[2][64 * 64];   // [key][d], swizzled
  __align__(16) __shared__ ushort_t Vt[2][64 * 64];   // [d][key], swizzled
  __shared__ float biasL[2][64];
  __align__(16) __shared__ ushort_t Pl[4][16 * 72];   // per-wave P bounce

  const int qrow_b = qt * 64 + wave * 16 + lq;        // within-batch q index
  const size_t qoff = (size_t)(b * N_ + qrow_b) * D_;
  short8 qf0 = *(const short8*)&q[qoff + g * 8];
  short8 qf1 = *(const short8*)&q[qoff + 32 + g * 8];
  const float qb = biasf[b * N_ + qrow_b];            // 0 or -1e30 (dead q row)

  float m = -INFINITY, lsum = 0.f;
  f32x4 o[4];
  #pragma unroll
  for (int i = 0; i < 4; ++i) o[i] = f32x4{0.f, 0.f, 0.f, 0.f};

  const int r0 = t >> 3, j0 = t & 7;   // staging chunk t   -> rows 0..31
  const int r1 = 32 + (t >> 3);        // staging chunk 256+t -> rows 32..63

  uint4 k0, k1, v0, v1; float bb = 0.f;

  auto stage_load = [&](int tile) {
    const int jb = (tile_lo + tile) * 64;
    const ushort_t* kbase = kk + (size_t)(b * N_ + jb) * D_;
    k0 = *(const uint4*)&kbase[(size_t)r0 * D_ + j0 * 8];
    k1 = *(const uint4*)&kbase[(size_t)r1 * D_ + j0 * 8];
    const ushort_t* vbase = vt + (size_t)b * D_ * N_ + jb;
    v0 = *(const uint4*)&vbase[(size_t)r0 * N_ + j0 * 8];
    v1 = *(const uint4*)&vbase[(size_t)r1 * N_ + j0 * 8];
    if (t < 64) bb = biasf[b * N_ + jb + t];
  };
  auto stage_write = [&](int bufi) {
    *(uint4*)&Kt[bufi][r0 * 64 + ((j0 ^ (r0 & 7)) * 8)] = k0;
    *(uint4*)&Kt[bufi][r1 * 64 + ((j0 ^ (r1 & 7)) * 8)] = k1;
    *(uint4*)&Vt[bufi][r0 * 64 + ((j0 ^ (r0 & 7)) * 8)] = v0;
    *(uint4*)&Vt[bufi][r1 * 64 + ((j0 ^ (r1 & 7)) * 8)] = v1;
    if (t < 64) biasL[bufi][t] = bb;
  };

  stage_load(0);
  stage_write(0);
  __syncthreads();

  for (int it = 0; it < nit; ++it) {
    const int bufi = it & 1;
    const int jb = (tile_lo + it) * 64;
    const bool more = (it + 1 < nit);
    if (more) stage_load(it + 1);      // VMEM in flight across compute (T14)

    // ---- QK^T (swapped: C rows = keys, cols = q) ----
    f32x4 st[4];
    #pragma unroll
    for (int kc = 0; kc < 4; ++kc) st[kc] = f32x4{0.f, 0.f, 0.f, 0.f};
    #pragma unroll
    for (int kc = 0; kc < 4; ++kc) {
      const int row = kc * 16 + lq, sw = row & 7;
      short8 a0 = *(const short8*)&Kt[bufi][row * 64 + ((g ^ sw) * 8)];
      st[kc] = __builtin_amdgcn_mfma_f32_16x16x32_bf16(a0, qf0, st[kc], 0, 0, 0);
      short8 a1 = *(const short8*)&Kt[bufi][row * 64 + (((4 + g) ^ sw) * 8)];
      st[kc] = __builtin_amdgcn_mfma_f32_16x16x32_bf16(a1, qf1, st[kc], 0, 0, 0);
    }

    // ---- masking + online softmax (lane owns q=lq, 16 keys) ----
    float sv[16];
    float tm = -INFINITY;
    #pragma unroll
    for (int kc = 0; kc < 4; ++kc) {
      float4 bf = *(const float4*)&biasL[bufi][kc * 16 + 4 * g];
      #pragma unroll
      for (int r = 0; r < 4; ++r) {
        const int klocal = kc * 16 + 4 * g + r;
        const float bv = (r == 0 ? bf.x : r == 1 ? bf.y : r == 2 ? bf.z : bf.w);
        float z = fmaf(st[kc][r], SCALE, bv);  // masked key -> exactly -1e30
        z += qb;                               // dead q row -> -1e30 or -2e30
        z = fmaxf(z, MASKVAL);                 // re-clamp to exactly -1e30
        z = (jb + klocal == qrow_b) ? MASKVAL : z;  // diagonal exclusion
        sv[kc * 4 + r] = z;
        tm = fmaxf(tm, z);
      }
    }
    tm = fmaxf(tm, __shfl_xor(tm, 16, 64));
    tm = fmaxf(tm, __shfl_xor(tm, 32, 64));
    const float mnew = fmaxf(m, tm);
    const float corr = __expf(m - mnew);

    float ps = 0.f;
    unsigned pw[8];
    #pragma unroll
    for (int h = 0; h < 8; ++h) {
      float pa = __expf(sv[2 * h] - mnew);
      float pb = __expf(sv[2 * h + 1] - mnew);
      ps += pa + pb;
      pw[h] = (unsigned)f2bf(pa) | ((unsigned)f2bf(pb) << 16);
    }
    ps += __shfl_xor(ps, 16, 64);
    ps += __shfl_xor(ps, 32, 64);
    lsum = lsum * corr + ps;
    m = mnew;

    // ---- P bounce to per-wave LDS ----
    #pragma unroll
    for (int kc = 0; kc < 4; ++kc) {
      uint2 w; w.x = pw[kc * 2]; w.y = pw[kc * 2 + 1];
      *(uint2*)&Pl[wave][lq * 72 + kc * 16 + 4 * g] = w;
    }
    asm volatile("s_waitcnt lgkmcnt(0)" ::: "memory");
    __builtin_amdgcn_sched_barrier(0);

    // ---- rescale O (O rows q = 4g + r) ----
    const float c0 = __shfl(corr, g * 4 + 0, 64);
    const float c1 = __shfl(corr, g * 4 + 1, 64);
    const float c2 = __shfl(corr, g * 4 + 2, 64);
    const float c3 = __shfl(corr, g * 4 + 3, 64);
    #pragma unroll
    for (int dc = 0; dc < 4; ++dc) {
      o[dc][0] *= c0; o[dc][1] *= c1; o[dc][2] *= c2; o[dc][3] *= c3;
    }

    // ---- PV ----
    short8 pf0 = *(const short8*)&Pl[wave][lq * 72 + g * 8];
    short8 pf1 = *(const short8*)&Pl[wave][lq * 72 + 32 + g * 8];
    #pragma unroll
    for (int dc = 0; dc < 4; ++dc) {
      const int row = dc * 16 + lq, sw = row & 7;
      short8 vv0 = *(const short8*)&Vt[bufi][row * 64 + ((g ^ sw) * 8)];
      o[dc] = __builtin_amdgcn_mfma_f32_16x16x32_bf16(pf0, vv0, o[dc], 0, 0, 0);
      short8 vv1 = *(const short8*)&Vt[bufi][row * 64 + (((4 + g) ^ sw) * 8)];
      o[dc] = __builtin_amdgcn_mfma_f32_16x16x32_bf16(pf1, vv1, o[dc], 0, 0, 0);
    }

    if (more) stage_write(bufi ^ 1);   // compiler inserts vmcnt before ds_write
    __syncthreads();
  }

  // ---- epilogue: unnormalized O' + (m,l) ----
  float* obase = (sp == 0 ? op0 : opws + (size_t)(sp - 1) * (B_ * N_) * D_)
               + ((size_t)(b * N_) + qt * 64 + wave * 16) * D_;
  #pragma unroll
  for (int dc = 0; dc < 4; ++dc) {
    #pragma unroll
    for (int r = 0; r < 4; ++r)
      obase[(size_t)(g * 4 + r) * D_ + dc * 16 + lq] = o[dc][r];
  }
  if (g == 0) {
    float* mlp = mlbuf + ((size_t)sp * (B_ * N_) + b * N_ + qt * 64 + wave * 16 + lq) * 2;
    mlp[0] = m; mlp[1] = lsum;
  }
}

// ---------------------------------------------------------------------------
// Merge: out[q][d] = sum_s O'_s[q][d] * e^{m_s - M} / sum_s l_s e^{m_s - M}.
// Slice 0 lives in d_out (in-place normalize; each thread reads its own
// elements before writing them).
// ---------------------------------------------------------------------------
__global__ __launch_bounds__(256) void merge_kernel(
    const float* __restrict__ op0, const float* __restrict__ opws,
    const float* __restrict__ mlbuf, float* __restrict__ out, int nsplit)
{
  const int t = threadIdx.x;
  const int qrow = blockIdx.x * 16 + (t >> 4);
  const int d = (t & 15) * 4;

  float M = -INFINITY;
  for (int s = 0; s < nsplit; ++s)
    M = fmaxf(M, mlbuf[((size_t)s * (B_ * N_) + qrow) * 2]);

  float L = 0.f;
  float ax = 0.f, ay = 0.f, az = 0.f, aw = 0.f;
  for (int s = 0; s < nsplit; ++s) {
    const float* mlp = &mlbuf[((size_t)s * (B_ * N_) + qrow) * 2];
    const float w = __expf(mlp[0] - M);
    L += mlp[1] * w;
    const float* ob = (s == 0) ? op0 : opws + (size_t)(s - 1) * (B_ * N_) * D_;
    float4 ov = *(const float4*)&ob[(size_t)qrow * D_ + d];
    ax += ov.x * w; ay += ov.y * w; az += ov.z * w; aw += ov.w * w;
  }
  const float inv = 1.f / L;
  float4 res; res.x = ax * inv; res.y = ay * inv; res.z = az * inv; res.w = aw * inv;
  *(float4*)&out[(size_t)qrow * D_ + d] = res;
}

// ---------------------------------------------------------------------------
extern "C" void kernel_launch(void* const* d_in, const int* in_sizes, int n_in,
                              void* d_out, int out_size, void* d_ws, size_t ws_size,
                              hipStream_t stream) {
  (void)in_sizes; (void)n_in; (void)out_size;
  const float* Qv = (const float*)d_in[0];
  const float* Kv = (const float*)d_in[1];
  const float* Vv = (const float*)d_in[2];
  const int* mask = (const int*)d_in[3];
  const float* Wq = (const float*)d_in[4];
  const float* Wk = (const float*)d_in[5];
  const float* Wv = (const float*)d_in[6];
  float* out = (float*)d_out;

  ushort_t* qb_ = (ushort_t*)d_ws;                         // [B*N][64] bf16
  ushort_t* kb_ = qb_ + (size_t)B_ * N_ * D_;              // [B*N][64] bf16
  ushort_t* vtb = kb_ + (size_t)B_ * N_ * D_;              // [B][64][N] bf16
  float* biasf  = (float*)(vtb + (size_t)B_ * N_ * D_);    // [B*N] f32
  float* mlbuf  = biasf + (size_t)B_ * N_;                 // [3][B*N][2] f32 max
  float* opws   = mlbuf + (size_t)3 * B_ * N_ * 2;         // (nsplit-1) x [B*N][64] f32
  const size_t fixed_bytes = (size_t)((char*)opws - (char*)d_ws);
  const size_t slice_bytes = (size_t)B_ * N_ * D_ * sizeof(float);

  int nsplit = 1;
  if (ws_size >= fixed_bytes + 2 * slice_bytes) nsplit = 3;
  else if (ws_size >= fixed_bytes + 1 * slice_bytes) nsplit = 2;

  proj_kernel<<<dim3(256, 3), dim3(256), 0, stream>>>(
      Qv, Kv, Vv, Wq, Wk, Wv, mask, qb_, kb_, vtb, biasf);
  attn2_kernel<<<dim3(N_ / 64, B_, nsplit), dim3(256), 0, stream>>>(
      qb_, kb_, vtb, biasf, out, opws, mlbuf, nsplit);
  merge_kernel<<<dim3(B_ * N_ / 16), dim3(256), 0, stream>>>(
      out, opws, mlbuf, out, nsplit);
}